// Round 1
// baseline (3620.388 us; speedup 1.0000x reference)
//
#include <hip/hip_runtime.h>
#include <math.h>

#define B_ 32
#define DIN_ 3072
#define ENC_ 512
#define Z_ 256
#define M_ 64

// ---------------- encoder: h = tanh(x @ enc_W + enc_b), x(32,3072) W(3072,512) ----------------
__global__ void enc_kernel(const float* __restrict__ x, const float* __restrict__ W,
                           const float* __restrict__ b, float* __restrict__ h) {
  int col = blockIdx.x * 256 + threadIdx.x;   // [0,512)
  int row = blockIdx.y;                       // [0,32)  -> wave-uniform, x loads scalarize
  const float* xr = x + row * DIN_;
  float acc = 0.f;
#pragma unroll 8
  for (int k = 0; k < DIN_; ++k) acc += xr[k] * W[k * ENC_ + col];
  h[row * ENC_ + col] = tanhf(acc + b[col]);
}

// ---------------- generic: out(32,N) = act(A(32,K) @ W(K,N) + bias) ----------------
// block 256 = 64 cols x 4 groups (8 batch rows each). A staged transposed in LDS (stride 36,
// 16B-aligned float4 reads, banks spread). ACT: 0 none, 1 tanh, 2 softplus+clip.
template <int K, int ACT>
__global__ void gemm_at(const float* __restrict__ A, const float* __restrict__ W,
                        const float* __restrict__ bias, float* __restrict__ out, int N) {
  __shared__ float AT[K * 36];
  int t = threadIdx.x;
  for (int idx = t; idx < 32 * K; idx += 256) {
    int b = idx / K, k = idx - b * K;
    AT[k * 36 + b] = A[idx];
  }
  __syncthreads();
  int col = blockIdx.x * 64 + (t & 63);
  int g = t >> 6;
  float acc[8];
#pragma unroll
  for (int i = 0; i < 8; ++i) acc[i] = 0.f;
  const float* Wc = W + col;
  for (int k = 0; k < K; ++k) {
    float w = Wc[(size_t)k * N];
    const float4* a4 = (const float4*)&AT[k * 36 + g * 8];
    float4 a0 = a4[0], a1 = a4[1];
    acc[0] += a0.x * w; acc[1] += a0.y * w; acc[2] += a0.z * w; acc[3] += a0.w * w;
    acc[4] += a1.x * w; acc[5] += a1.y * w; acc[6] += a1.z * w; acc[7] += a1.w * w;
  }
  float bv = bias[col];
#pragma unroll
  for (int i = 0; i < 8; ++i) {
    int b = g * 8 + i;
    float v = acc[i] + bv;
    if (ACT == 1) v = tanhf(v);
    else if (ACT == 2) {
      float sp = (v > 20.f) ? v : log1pf(expf(v));
      v = fminf(fmaxf(sp, 1e-4f), 5.f);
    }
    out[(size_t)b * N + col] = v;
  }
}

// ---------------- z0 = eps*sqrt(var) + mu ----------------
__global__ void z0_kernel(const float* __restrict__ eps, const float* __restrict__ mu,
                          const float* __restrict__ var, float* __restrict__ z0) {
  int i = blockIdx.x * 256 + threadIdx.x;
  z0[i] = eps[i] * sqrtf(var[i]) + mu[i];
}

// ---------------- 100-step Newton-Schulz orthogonalization, one 256x64 matrix per block ----------
// Qs padded to stride 68 floats (16B aligned rows, banks spread for both row & col access).
__launch_bounds__(512, 1)
__global__ void qscan_kernel(float* __restrict__ Q) {
  __shared__ float Qs[256 * 68];   // 69.6 KB
  __shared__ float As[64 * 68];    // 17.4 KB
  __shared__ float red[8];
  int t = threadIdx.x;
  float* Qg = Q + (size_t)blockIdx.x * (Z_ * M_);
  for (int idx = t; idx < Z_ * M_; idx += 512)
    Qs[(idx >> 6) * 68 + (idx & 63)] = Qg[idx];
  __syncthreads();
  // Frobenius norm
  float ss = 0.f;
  for (int idx = t; idx < Z_ * M_; idx += 512) {
    float v = Qs[(idx >> 6) * 68 + (idx & 63)];
    ss += v * v;
  }
#pragma unroll
  for (int off = 32; off > 0; off >>= 1) ss += __shfl_down(ss, off, 64);
  if ((t & 63) == 0) red[t >> 6] = ss;
  __syncthreads();
  float tot = 0.f;
#pragma unroll
  for (int i = 0; i < 8; ++i) tot += red[i];
  float rn = 1.f / sqrtf(tot);
  for (int idx = t; idx < Z_ * M_; idx += 512)
    Qs[(idx >> 6) * 68 + (idx & 63)] *= rn;
  __syncthreads();

  const int tm = t & 15, tp = t >> 4;          // prod tile: rows 4*tm.., cols 2*tp..
  const int z = t & 255, half = t >> 8, c0 = half * 32;  // mm: row z, col half

  for (int step = 0; step < 100; ++step) {
    // ---- prod = Q^T Q (4x2 register tile), A = 1.5 I - 0.5 prod ----
    float p00 = 0, p01 = 0, p10 = 0, p11 = 0, p20 = 0, p21 = 0, p30 = 0, p31 = 0;
    for (int zz = 0; zz < 256; ++zz) {
      const float* rowp = &Qs[zz * 68];
      float4 qa = *(const float4*)&rowp[4 * tm];
      float2 qb = *(const float2*)&rowp[2 * tp];
      p00 += qa.x * qb.x; p01 += qa.x * qb.y;
      p10 += qa.y * qb.x; p11 += qa.y * qb.y;
      p20 += qa.z * qb.x; p21 += qa.z * qb.y;
      p30 += qa.w * qb.x; p31 += qa.w * qb.y;
    }
    {
      int m0 = 4 * tm, q0 = 2 * tp;
      As[(m0 + 0) * 68 + q0]     = ((m0 + 0) == q0     ? 1.5f : 0.f) - 0.5f * p00;
      As[(m0 + 0) * 68 + q0 + 1] = ((m0 + 0) == q0 + 1 ? 1.5f : 0.f) - 0.5f * p01;
      As[(m0 + 1) * 68 + q0]     = ((m0 + 1) == q0     ? 1.5f : 0.f) - 0.5f * p10;
      As[(m0 + 1) * 68 + q0 + 1] = ((m0 + 1) == q0 + 1 ? 1.5f : 0.f) - 0.5f * p11;
      As[(m0 + 2) * 68 + q0]     = ((m0 + 2) == q0     ? 1.5f : 0.f) - 0.5f * p20;
      As[(m0 + 2) * 68 + q0 + 1] = ((m0 + 2) == q0 + 1 ? 1.5f : 0.f) - 0.5f * p21;
      As[(m0 + 3) * 68 + q0]     = ((m0 + 3) == q0     ? 1.5f : 0.f) - 0.5f * p30;
      As[(m0 + 3) * 68 + q0 + 1] = ((m0 + 3) == q0 + 1 ? 1.5f : 0.f) - 0.5f * p31;
    }
    __syncthreads();
    // ---- Qnew = Q @ A : each thread owns row z, 32 cols ----
    float outv[32];
#pragma unroll
    for (int i = 0; i < 32; ++i) outv[i] = 0.f;
    const float* qrow = &Qs[z * 68];
    for (int k = 0; k < 64; k += 4) {
      float4 q4 = *(const float4*)&qrow[k];
      float qk[4] = {q4.x, q4.y, q4.z, q4.w};
#pragma unroll
      for (int kk = 0; kk < 4; ++kk) {
        const float* arow = &As[(k + kk) * 68 + c0];
        float qv = qk[kk];
#pragma unroll
        for (int c = 0; c < 8; ++c) {
          float4 a4 = *(const float4*)&arow[4 * c];
          outv[4 * c + 0] += qv * a4.x;
          outv[4 * c + 1] += qv * a4.y;
          outv[4 * c + 2] += qv * a4.z;
          outv[4 * c + 3] += qv * a4.w;
        }
      }
    }
    __syncthreads();   // all reads of Qs done before overwrite
    float* wrow = &Qs[z * 68 + c0];
#pragma unroll
    for (int c = 0; c < 8; ++c)
      *(float4*)&wrow[4 * c] = make_float4(outv[4 * c], outv[4 * c + 1],
                                           outv[4 * c + 2], outv[4 * c + 3]);
    __syncthreads();
  }
  for (int idx = t; idx < Z_ * M_; idx += 512)
    Qg[idx] = Qs[(idx >> 6) * 68 + (idx & 63)];
}

// ---------------- Sylvester flow: 8 sequential steps, one block per batch row ----------------
// Uses factored forms: v = z^T q; pre[n] = sum_{m>n} v[m]*Rt[n,m] + v[n]*d2 + bf;
// w[m] = sum_{n>m} R[m,n]*hk[n] + d1*hk[m]; z += q @ w.
__launch_bounds__(256, 1)
__global__ void flow_kernel(const float* __restrict__ Qk, const float* __restrict__ Rr,
                            const float* __restrict__ Rtr, const float* __restrict__ bf,
                            const float* __restrict__ d1t, const float* __restrict__ d2t,
                            const float* __restrict__ z0, float* __restrict__ z_out,
                            float* __restrict__ ldj_out) {
  __shared__ float qs[256 * 65];   // 66.6 KB, stride 65 spreads column reads across banks
  __shared__ float zs[256];
  __shared__ float vpart[4][64];
  __shared__ float vs[64];
  __shared__ float hks[64];
  __shared__ float wvec[64];
  int t = threadIdx.x;
  int b = blockIdx.x;
  zs[t] = z0[b * 256 + t];
  float ldj_acc = 0.f;
  for (int k = 0; k < 8; ++k) {
    __syncthreads();
    const float* qg = Qk + (size_t)(b * 8 + k) * (Z_ * M_);
    for (int idx = t; idx < Z_ * M_; idx += 256)
      qs[(idx >> 6) * 65 + (idx & 63)] = qg[idx];
    __syncthreads();
    {  // v partial sums: 4 z-chunks x 64 m
      int m = t & 63, c = t >> 6, zb = c * 64;
      float s = 0.f;
      for (int zz = 0; zz < 64; ++zz) s += zs[zb + zz] * qs[(zb + zz) * 65 + m];
      vpart[c][m] = s;
    }
    __syncthreads();
    if (t < 64) vs[t] = vpart[0][t] + vpart[1][t] + vpart[2][t] + vpart[3][t];
    __syncthreads();
    if (t < 64) {
      int n = t;
      float pre = bf[(b * 64 + n) * 8 + k];
      const float* rtrow = Rtr + (size_t)(b * 64 + n) * 64 * 8 + k;
      for (int m = n + 1; m < 64; ++m) pre += vs[m] * rtrow[m * 8];
      float d2v = d2t[(b * 64 + n) * 8 + k];
      pre += vs[n] * d2v;
      float hk = tanhf(pre);
      hks[n] = hk;
      float d1v = d1t[(b * 64 + n) * 8 + k];
      float diag = 1.f + (1.f - hk * hk) * d1v * d2v;
      ldj_acc += logf(fabsf(diag));
    }
    __syncthreads();
    if (t < 64) {
      int m = t;
      const float* rrow = Rr + (size_t)(b * 64 + m) * 64 * 8 + k;
      float w = d1t[(b * 64 + m) * 8 + k] * hks[m];
      for (int n = m + 1; n < 64; ++n) w += rrow[n * 8] * hks[n];
      wvec[m] = w;
    }
    __syncthreads();
    {
      float s = 0.f;
      const float* qrow = &qs[t * 65];
#pragma unroll 8
      for (int m = 0; m < 64; ++m) s += qrow[m] * wvec[m];
      zs[t] += s;
    }
  }
  __syncthreads();
  z_out[b * 256 + t] = zs[t];
  if (t < 64) {
    float v = ldj_acc;
#pragma unroll
    for (int off = 32; off > 0; off >>= 1) v += __shfl_down(v, off, 64);
    if (t == 0) ldj_out[b] = v;
  }
}

extern "C" void kernel_launch(void* const* d_in, const int* in_sizes, int n_in,
                              void* d_out, int out_size, void* d_ws, size_t ws_size,
                              hipStream_t stream) {
  const float* x     = (const float*)d_in[0];
  const float* eps   = (const float*)d_in[1];
  const float* enc_W = (const float*)d_in[2];
  const float* enc_b = (const float*)d_in[3];
  const float* mu_W  = (const float*)d_in[4];
  const float* mu_b  = (const float*)d_in[5];
  const float* var_W = (const float*)d_in[6];
  const float* var_b = (const float*)d_in[7];
  const float* q_W   = (const float*)d_in[8];
  const float* q_b   = (const float*)d_in[9];
  const float* bf_W  = (const float*)d_in[10];
  const float* bf_b  = (const float*)d_in[11];
  const float* r_W   = (const float*)d_in[12];
  const float* r_b   = (const float*)d_in[13];
  const float* rt_W  = (const float*)d_in[14];
  const float* rt_b  = (const float*)d_in[15];
  const float* d1_W  = (const float*)d_in[16];
  const float* d1_b  = (const float*)d_in[17];
  const float* d2_W  = (const float*)d_in[18];
  const float* d2_b  = (const float*)d_in[19];
  const float* dec_W = (const float*)d_in[20];
  const float* dec_b = (const float*)d_in[21];
  const float* pmu_W = (const float*)d_in[22];
  const float* pmu_b = (const float*)d_in[23];

  float* out   = (float*)d_out;
  float* xm_o  = out;               // 32*3072 = 98304
  float* mu_o  = out + 98304;       // 8192
  float* var_o = out + 106496;      // 8192
  float* ldj_o = out + 114688;      // 32
  float* z0_o  = out + 114720;      // 8192
  float* z_o   = out + 122912;      // 8192

  float* ws   = (float*)d_ws;
  float* h_w  = ws;                  // 16384
  float* Q_w  = h_w + 16384;         // 4194304  (256 matrices of 256x64)
  float* R_w  = Q_w + 4194304;       // 1048576
  float* Rt_w = R_w + 1048576;       // 1048576
  float* bf_w = Rt_w + 1048576;      // 16384
  float* d1_w = bf_w + 16384;        // 16384 (tanh applied)
  float* d2_w = d1_w + 16384;        // 16384 (tanh applied)
  float* hd_w = d2_w + 16384;        // 32768

  enc_kernel<<<dim3(2, 32), 256, 0, stream>>>(x, enc_W, enc_b, h_w);

  gemm_at<512, 0><<<dim3(2048), 256, 0, stream>>>(h_w, q_W, q_b, Q_w, 131072);
  gemm_at<512, 0><<<dim3(4),    256, 0, stream>>>(h_w, mu_W, mu_b, mu_o, 256);
  gemm_at<512, 2><<<dim3(4),    256, 0, stream>>>(h_w, var_W, var_b, var_o, 256);
  gemm_at<512, 0><<<dim3(8),    256, 0, stream>>>(h_w, bf_W, bf_b, bf_w, 512);
  gemm_at<512, 0><<<dim3(512),  256, 0, stream>>>(h_w, r_W, r_b, R_w, 32768);
  gemm_at<512, 0><<<dim3(512),  256, 0, stream>>>(h_w, rt_W, rt_b, Rt_w, 32768);
  gemm_at<512, 1><<<dim3(8),    256, 0, stream>>>(h_w, d1_W, d1_b, d1_w, 512);
  gemm_at<512, 1><<<dim3(8),    256, 0, stream>>>(h_w, d2_W, d2_b, d2_w, 512);

  z0_kernel<<<dim3(32), 256, 0, stream>>>(eps, mu_o, var_o, z0_o);

  qscan_kernel<<<dim3(256), 512, 0, stream>>>(Q_w);

  flow_kernel<<<dim3(32), 256, 0, stream>>>(Q_w, R_w, Rt_w, bf_w, d1_w, d2_w,
                                            z0_o, z_o, ldj_o);

  gemm_at<256, 1><<<dim3(16), 256, 0, stream>>>(z_o, dec_W, dec_b, hd_w, 1024);
  gemm_at<1024, 0><<<dim3(48), 256, 0, stream>>>(hd_w, pmu_W, pmu_b, xm_o, 3072);
}